// Round 7
// baseline (868.287 us; speedup 1.0000x reference)
//
#include <hip/hip_runtime.h>

#define V 512
#define L 168
#define PLANE 86016          // V*L
#define CHSTRIDE 2752512     // 32*512*168 elements per batch
#define NFLAT 5376           // 32*168
#define B_ 16
#define HDRB (1u << 20)      // ATb (512 KB) + Wb (8 KB), padded to 1 MiB

typedef __attribute__((ext_vector_type(8))) short s16x8;
typedef __attribute__((ext_vector_type(4))) float f32x4;
typedef unsigned short u16;

__device__ inline short f2bf(float f) {
    unsigned u = __builtin_bit_cast(unsigned, f);
    u += 0x7FFF + ((u >> 16) & 1);
    return (short)(u >> 16);
}

// ---- prep: ATb[w][v] = bf16(rownorm adj^T); Wb = folded W' (mix absorbed) ----
// out = b + W0'p0 + W1'p1 + W2'p2 + W3'p3,  p0=x, pk=A p_{k-1}
__global__ __launch_bounds__(256) void prep_b(const float* __restrict__ adj,
                                              const float* __restrict__ W,
                                              u16* __restrict__ ATb,
                                              u16* __restrict__ Wb) {
    if (blockIdx.x == V) {
        const float al = 0.05f, be = 0.95f;
        for (int i = threadIdx.x; i < 1024; i += 256) {
            const int o = i >> 5, c = i & 31;
            const float w0 = W[o * 128 + c];
            const float w1 = W[o * 128 + 32 + c];
            const float w2 = W[o * 128 + 64 + c];
            const float w3 = W[o * 128 + 96 + c];
            Wb[o * 128 + c]      = f2bf(w0 + al * (w1 + w2 + w3));
            Wb[o * 128 + 32 + c] = f2bf(be * (w1 + al * (w2 + w3)));
            Wb[o * 128 + 64 + c] = f2bf(be * be * (w2 + al * w3));
            Wb[o * 128 + 96 + c] = f2bf(be * be * be * w3);
        }
        return;
    }
    const int v = blockIdx.x;
    float s = 0.f;
    for (int w = threadIdx.x; w < V; w += 256)
        s += adj[v * V + w] + (w == v ? 1.f : 0.f);
    __shared__ float red[256];
    red[threadIdx.x] = s;
    __syncthreads();
    for (int off = 128; off > 0; off >>= 1) {
        if ((int)threadIdx.x < off) red[threadIdx.x] += red[threadIdx.x + off];
        __syncthreads();
    }
    const float inv = 1.f / red[0];
    for (int w = threadIdx.x; w < V; w += 256)
        ATb[w * V + v] = f2bf((adj[v * V + w] + (w == v ? 1.f : 0.f)) * inv);
}

// ---- cvtT: xa[b][n=(c,l)][v] = bf16(x[b][c][v][l]) — LDS-tiled transpose -----
// Both global sides fully coalesced; LDS f32 [64][65] breaks bank conflicts.
__global__ __launch_bounds__(256) void cvtT(const float* __restrict__ x,
                                            u16* __restrict__ xa) {
    const int b = blockIdx.z >> 5, c = blockIdx.z & 31;
    const int v0 = blockIdx.y * 64, l0 = blockIdx.x * 64;
    const int tid = threadIdx.x;
    __shared__ float T[64][65];
    const float* xp = x + (size_t)b * CHSTRIDE + (size_t)c * PLANE;
    u16* xo = xa + (size_t)b * CHSTRIDE + (size_t)c * L * 512;

#pragma unroll
    for (int rep = 0; rep < 16; rep++) {
        const int idx = rep * 256 + tid;
        const int vv = idx >> 6, ll = idx & 63;       // read: l-contiguous lanes
        if (l0 + ll < L) T[vv][ll] = xp[(size_t)(v0 + vv) * L + l0 + ll];
    }
    __syncthreads();
#pragma unroll
    for (int rep = 0; rep < 16; rep++) {
        const int idx = rep * 256 + tid;
        const int ll = idx >> 6, vv = idx & 63;       // write: v-contiguous lanes
        if (l0 + ll < L)
            xo[(size_t)(l0 + ll) * 512 + v0 + vv] = f2bf(T[vv][ll]);
    }
}

// ---- prop: dst = bf16(AT @ src), all buffers [n][v] — NO LDS, NO barriers ----
// Block: D[w: 256][n: 64]; wave owns 64 w x 64 n. B-frags = 16B direct global
// (v-contiguous); A-frags = 16B direct from L2-resident ATb.
__global__ __launch_bounds__(256, 2) void prop_g(const u16* __restrict__ src,
                                                 const u16* __restrict__ ATb,
                                                 u16* __restrict__ dst) {
    const int b = blockIdx.z, w0 = blockIdx.y * 256, n0 = blockIdx.x * 64;
    const int tid = threadIdx.x, lane = tid & 63, wave = tid >> 6;
    const int colb = lane & 15, kg = lane >> 4;
    const size_t sB = (size_t)b * CHSTRIDE;
    const u16* srcb = src + sB;

    f32x4 acc[4][4];
#pragma unroll
    for (int i = 0; i < 4; i++)
#pragma unroll
        for (int j = 0; j < 4; j++) acc[i][j] = (f32x4){0.f, 0.f, 0.f, 0.f};

    const int arow = w0 + wave * 64 + colb;          // + mt*16
    const int brow = n0 + colb;                      // + nt*16

#pragma unroll 4
    for (int kk = 0; kk < 16; kk++) {
        const int v = kk * 32 + kg * 8;
        s16x8 afr[4], bfr[4];
#pragma unroll
        for (int mt = 0; mt < 4; mt++)
            afr[mt] = *(const s16x8*)&ATb[(size_t)(arow + mt * 16) * 512 + v];
#pragma unroll
        for (int nt = 0; nt < 4; nt++)
            bfr[nt] = *(const s16x8*)&srcb[(size_t)(brow + nt * 16) * 512 + v];
#pragma unroll
        for (int mt = 0; mt < 4; mt++)
#pragma unroll
            for (int nt = 0; nt < 4; nt++)
                acc[mt][nt] = __builtin_amdgcn_mfma_f32_16x16x32_bf16(afr[mt], bfr[nt],
                                                                      acc[mt][nt], 0, 0, 0);
    }

    // store [n][v]: lane (nt,colb) col n, rows w = base + kg*4 + r  → one 8B store
#pragma unroll
    for (int mt = 0; mt < 4; mt++) {
        const int wrow = w0 + wave * 64 + mt * 16 + kg * 4;
#pragma unroll
        for (int nt = 0; nt < 4; nt++) {
            ushort4 pk;
            pk.x = (u16)f2bf(acc[mt][nt][0]);
            pk.y = (u16)f2bf(acc[mt][nt][1]);
            pk.z = (u16)f2bf(acc[mt][nt][2]);
            pk.w = (u16)f2bf(acc[mt][nt][3]);
            *(ushort4*)&dst[sB + (size_t)(n0 + nt * 16 + colb) * 512 + wrow] = pk;
        }
    }
}

// ---- outconv: out = bias + W' @ [xa,p1,p2,p3]  (all [n][v] bf16) -------------
// Block: pos-tile = 32 v x 2 l (64 pos); D[o:32][pos:64]; LDS slab [kcoct][pos][8].
__global__ __launch_bounds__(256) void outconv_g(const u16* __restrict__ xa,
                                                 const u16* __restrict__ p1,
                                                 const u16* __restrict__ p2,
                                                 const u16* __restrict__ p3,
                                                 const u16* __restrict__ Wb,
                                                 const float* __restrict__ bias,
                                                 float* __restrict__ out) {
    const int b = blockIdx.y;
    const int vt = blockIdx.x & 15, lt = blockIdx.x >> 4;
    const int v0 = vt * 32, l0 = lt * 2;
    const int tid = threadIdx.x, lane = tid & 63, wave = tid >> 6;
    const int colb = lane & 15, kg = lane >> 4;
    __shared__ u16 Hs[16 * 64 * 8];                  // 16 KB
    const size_t sB = (size_t)b * CHSTRIDE;
    const u16* bufs[4] = {xa, p1, p2, p3};

    {
        const int pi = tid & 63;
        const int v = v0 + (pi & 31), l = l0 + (pi >> 5);
#pragma unroll
        for (int p = 0; p < 4; p++) {
            const int m = wave + p * 4;              // buf p, channels wave*8..+7
            const u16* srcp = bufs[p] + sB + (size_t)(wave * 8 * L + l) * 512 + v;
            s16x8 t;
#pragma unroll
            for (int j = 0; j < 8; j++) t[j] = (short)srcp[(size_t)j * L * 512];
            *(s16x8*)&Hs[m * 512 + pi * 8] = t;
        }
    }
    __syncthreads();

    f32x4 acc[2];
    acc[0] = (f32x4){0.f, 0.f, 0.f, 0.f};
    acc[1] = acc[0];
#pragma unroll
    for (int kk = 0; kk < 4; kk++) {
        const s16x8 bfr = *(const s16x8*)&Hs[(kk * 4 + kg) * 512 + (wave * 16 + colb) * 8];
#pragma unroll
        for (int mt = 0; mt < 2; mt++) {
            const s16x8 afr = *(const s16x8*)&Wb[(mt * 16 + colb) * 128 + kk * 32 + kg * 8];
            acc[mt] = __builtin_amdgcn_mfma_f32_16x16x32_bf16(afr, bfr, acc[mt], 0, 0, 0);
        }
    }

    const int pi = wave * 16 + colb;
    const int v = v0 + (pi & 31), l = l0 + (pi >> 5);
#pragma unroll
    for (int mt = 0; mt < 2; mt++)
#pragma unroll
        for (int r = 0; r < 4; r++) {
            const int o = mt * 16 + kg * 4 + r;
            out[sB + (size_t)o * PLANE + (size_t)v * L + l] = bias[o] + acc[mt][r];
        }
}

extern "C" void kernel_launch(void* const* d_in, const int* in_sizes, int n_in,
                              void* d_out, int out_size, void* d_ws, size_t ws_size,
                              hipStream_t stream) {
    const float* x = (const float*)d_in[0];
    const float* adj = (const float*)d_in[1];
    const float* W = (const float*)d_in[2];
    const float* bias = (const float*)d_in[3];
    float* out = (float*)d_out;

    char* ws = (char*)d_ws;
    u16* ATb = (u16*)ws;
    u16* Wb = (u16*)(ws + 524288);
    u16* hbuf = (u16*)(ws + HDRB);

    prep_b<<<V + 1, 256, 0, stream>>>(adj, W, ATb, Wb);

    const size_t perBuf = (size_t)CHSTRIDE * 2;      // bytes per batch per bf16 buffer
    const size_t avail = ws_size > HDRB ? ws_size - HDRB : 0;
    int nbc = (int)(avail / (4 * perBuf));           // xa + p1 + p2 + p3
    if (nbc < 1) nbc = 1;                            // requires ws >= ~23 MB
    if (nbc > B_) nbc = B_;

    for (int b0 = 0; b0 < B_; b0 += nbc) {
        const int nb = (B_ - b0 < nbc) ? (B_ - b0) : nbc;
        const float* xb = x + (size_t)b0 * CHSTRIDE;
        float* outb = out + (size_t)b0 * CHSTRIDE;
        u16* xa = hbuf;
        u16* p1 = hbuf + (size_t)nbc * CHSTRIDE;
        u16* p2 = hbuf + (size_t)2 * nbc * CHSTRIDE;
        u16* p3 = hbuf + (size_t)3 * nbc * CHSTRIDE;

        cvtT<<<dim3(3, 8, nb * 32), 256, 0, stream>>>(xb, xa);

        const dim3 pg(NFLAT / 64, 2, nb);            // (84, 2, nb)
        prop_g<<<pg, 256, 0, stream>>>(xa, ATb, p1);
        prop_g<<<pg, 256, 0, stream>>>(p1, ATb, p2);
        prop_g<<<pg, 256, 0, stream>>>(p2, ATb, p3);

        outconv_g<<<dim3(16 * 84, nb), 256, 0, stream>>>(xa, p1, p2, p3, Wb, bias, outb);
    }
}

// Round 8
// 537.131 us; speedup vs baseline: 1.6165x; 1.6165x over previous
//
#include <hip/hip_runtime.h>

#define V 512
#define L 168
#define PLANE 86016          // V*L
#define CHSTRIDE 2752512     // 32*512*168 elements per batch
#define NFLAT 5376           // 32*168
#define B_ 16
#define HDRB (1u << 20)      // ATb (512 KB) + Wb (8 KB), padded to 1 MiB

typedef __attribute__((ext_vector_type(8))) short s16x8;
typedef __attribute__((ext_vector_type(4))) float f32x4;
typedef unsigned short u16;

__device__ inline short f2bf(float f) {
    unsigned u = __builtin_bit_cast(unsigned, f);
    u += 0x7FFF + ((u >> 16) & 1);
    return (short)(u >> 16);
}

// ---- prep: ATb[w][v] = bf16(rownorm adj^T); Wb = folded W' (mix absorbed) ----
// out = b + W0'p0 + W1'p1 + W2'p2 + W3'p3,  p0=x, pk=A p_{k-1}
__global__ __launch_bounds__(256) void prep_b(const float* __restrict__ adj,
                                              const float* __restrict__ W,
                                              u16* __restrict__ ATb,
                                              u16* __restrict__ Wb) {
    if (blockIdx.x == V) {
        const float al = 0.05f, be = 0.95f;
        for (int i = threadIdx.x; i < 1024; i += 256) {
            const int o = i >> 5, c = i & 31;
            const float w0 = W[o * 128 + c];
            const float w1 = W[o * 128 + 32 + c];
            const float w2 = W[o * 128 + 64 + c];
            const float w3 = W[o * 128 + 96 + c];
            Wb[o * 128 + c]      = f2bf(w0 + al * (w1 + w2 + w3));
            Wb[o * 128 + 32 + c] = f2bf(be * (w1 + al * (w2 + w3)));
            Wb[o * 128 + 64 + c] = f2bf(be * be * (w2 + al * w3));
            Wb[o * 128 + 96 + c] = f2bf(be * be * be * w3);
        }
        return;
    }
    const int v = blockIdx.x;
    float s = 0.f;
    for (int w = threadIdx.x; w < V; w += 256)
        s += adj[v * V + w] + (w == v ? 1.f : 0.f);
    __shared__ float red[256];
    red[threadIdx.x] = s;
    __syncthreads();
    for (int off = 128; off > 0; off >>= 1) {
        if ((int)threadIdx.x < off) red[threadIdx.x] += red[threadIdx.x + off];
        __syncthreads();
    }
    const float inv = 1.f / red[0];
    for (int w = threadIdx.x; w < V; w += 256)
        ATb[w * V + v] = f2bf((adj[v * V + w] + (w == v ? 1.f : 0.f)) * inv);
}

// ---- prop: dst = bf16(AT @ src) — pure GEMM, A staged in LDS (4x reuse) -------
// Block: D[w: 256][n: 64]; 4 waves; wave owns 64 w x 64 n.
// A-LDS row pitch 144 B (9 quads, odd) -> both staging writes (8 lanes/quad)
// and frag reads (2 lanes/quad) are bank-optimal without XOR swizzle.
// B-LDS: interleaved [koct][n][8] as r5 (conflict-free b128).
template <bool SRCF32>
__global__ __launch_bounds__(256, 3) void prop_s(const void* __restrict__ src,
                                                 const u16* __restrict__ ATb,
                                                 u16* __restrict__ dst) {
    const int b = blockIdx.z, w0 = blockIdx.y * 256, n0 = blockIdx.x * 64;
    const int tid = threadIdx.x, lane = tid & 63, wave = tid >> 6;
    const int colb = lane & 15, kg = lane >> 4;
    __shared__ u16 As[256 * 72];     // 36864 B, row pitch 144 B
    __shared__ u16 Hs[8 * 64 * 8];   // 16384 B

    const int sn = tid & 63;
    const int sc = (n0 + sn) / L, sl = (n0 + sn) - sc * L;
    const size_t bH = (size_t)b * CHSTRIDE;
    const size_t srcCol = bH + (size_t)sc * PLANE + sl;

    f32x4 acc[4][4];
#pragma unroll
    for (int i = 0; i < 4; i++)
#pragma unroll
        for (int j = 0; j < 4; j++) acc[i][j] = (f32x4){0.f, 0.f, 0.f, 0.f};

    for (int v0 = 0; v0 < V; v0 += 64) {
        __syncthreads();   // protect previous iteration's LDS reads
        {   // stage A: one 128B row per thread, quad-staggered by pitch
            const u16* ag = &ATb[(size_t)(w0 + tid) * 512 + v0];
#pragma unroll
            for (int q = 0; q < 8; q++) {
                const s16x8 av = *(const s16x8*)(ag + q * 8);
                *(s16x8*)((char*)As + tid * 144 + q * 16) = av;
            }
        }
        {   // stage B: two kocts per thread (r5 scheme)
#pragma unroll
            for (int h2 = 0; h2 < 2; h2++) {
                const int koct = wave + h2 * 4;
                s16x8 t;
#pragma unroll
                for (int j = 0; j < 8; j++) {
                    const size_t off = srcCol + (size_t)(v0 + koct * 8 + j) * L;
                    if (SRCF32)
                        t[j] = f2bf(((const float*)src)[off]);
                    else
                        t[j] = (short)((const u16*)src)[off];
                }
                *(s16x8*)&Hs[koct * 512 + sn * 8] = t;
            }
        }
        __syncthreads();
#pragma unroll
        for (int kk = 0; kk < 2; kk++) {
            const int cq = kk * 4 + kg;            // chunk index 0..7
            s16x8 afr[4], bfr[4];
#pragma unroll
            for (int mt = 0; mt < 4; mt++) {
                const int wr = wave * 64 + mt * 16 + colb;
                afr[mt] = *(const s16x8*)((const char*)As + wr * 144 + cq * 16);
            }
#pragma unroll
            for (int nt = 0; nt < 4; nt++)
                bfr[nt] = *(const s16x8*)&Hs[cq * 512 + (nt * 16 + colb) * 8];
#pragma unroll
            for (int mt = 0; mt < 4; mt++)
#pragma unroll
                for (int nt = 0; nt < 4; nt++)
                    acc[mt][nt] = __builtin_amdgcn_mfma_f32_16x16x32_bf16(afr[mt], bfr[nt],
                                                                          acc[mt][nt], 0, 0, 0);
        }
    }

    // epilogue: pure bf16 store (verified D mapping: col=lane&15, row=4*kg+r)
#pragma unroll
    for (int mt = 0; mt < 4; mt++) {
        const int wrow0 = w0 + wave * 64 + mt * 16 + kg * 4;
#pragma unroll
        for (int nt = 0; nt < 4; nt++) {
            const int ncol = n0 + nt * 16 + colb;
            const int c = ncol / L, l = ncol - c * L;
            const size_t base = bH + (size_t)c * PLANE + l;
#pragma unroll
            for (int r = 0; r < 4; r++)
                dst[base + (size_t)(wrow0 + r) * L] = f2bf(acc[mt][nt][r]);
        }
    }
}

// ---- outconv: out = bias + W' @ [x(f32), p1, p2, p3]  (r5/r6-proven) ---------
__global__ __launch_bounds__(256) void outconv_b(const float* __restrict__ x,
                                                 const u16* __restrict__ p1,
                                                 const u16* __restrict__ p2,
                                                 const u16* __restrict__ p3,
                                                 const u16* __restrict__ Wb,
                                                 const float* __restrict__ bias,
                                                 float* __restrict__ out) {
    const int b = blockIdx.y, p0 = blockIdx.x * 64;
    const int tid = threadIdx.x, lane = tid & 63, wave = tid >> 6;
    const int colb = lane & 15, kg = lane >> 4;
    __shared__ u16 Hs[16 * 64 * 8];  // 16 KB
    const size_t bH = (size_t)b * CHSTRIDE;
    const u16* bufs[4] = {nullptr, p1, p2, p3};

    {
        const int pos = tid & 63;
#pragma unroll
        for (int p = 0; p < 4; p++) {
            const int m = wave + p * 4;     // kc octet; stage p, channels (m&3)*8..+7
            s16x8 t;
            if (p == 0) {
                const float* srcx = x + bH + (size_t)((m & 3) * 8) * PLANE + p0 + pos;
#pragma unroll
                for (int j = 0; j < 8; j++) t[j] = f2bf(srcx[(size_t)j * PLANE]);
            } else {
                const u16* srch = bufs[p] + bH + (size_t)((m & 3) * 8) * PLANE + p0 + pos;
#pragma unroll
                for (int j = 0; j < 8; j++) t[j] = (short)srch[(size_t)j * PLANE];
            }
            *(s16x8*)&Hs[m * 512 + pos * 8] = t;
        }
    }
    __syncthreads();

    f32x4 acc[2];
    acc[0] = (f32x4){0.f, 0.f, 0.f, 0.f};
    acc[1] = acc[0];
#pragma unroll
    for (int kk = 0; kk < 4; kk++) {
        const s16x8 bfr = *(const s16x8*)&Hs[(kk * 4 + kg) * 512 + (wave * 16 + colb) * 8];
#pragma unroll
        for (int mt = 0; mt < 2; mt++) {
            const s16x8 afr = *(const s16x8*)&Wb[(mt * 16 + colb) * 128 + kk * 32 + kg * 8];
            acc[mt] = __builtin_amdgcn_mfma_f32_16x16x32_bf16(afr, bfr, acc[mt], 0, 0, 0);
        }
    }
#pragma unroll
    for (int mt = 0; mt < 2; mt++)
#pragma unroll
        for (int r = 0; r < 4; r++) {
            const int o = mt * 16 + kg * 4 + r;
            out[bH + (size_t)o * PLANE + p0 + wave * 16 + colb] = bias[o] + acc[mt][r];
        }
}

extern "C" void kernel_launch(void* const* d_in, const int* in_sizes, int n_in,
                              void* d_out, int out_size, void* d_ws, size_t ws_size,
                              hipStream_t stream) {
    const float* x = (const float*)d_in[0];
    const float* adj = (const float*)d_in[1];
    const float* W = (const float*)d_in[2];
    const float* bias = (const float*)d_in[3];
    float* out = (float*)d_out;

    char* ws = (char*)d_ws;
    u16* ATb = (u16*)ws;
    u16* Wb = (u16*)(ws + 524288);
    u16* hbuf = (u16*)(ws + HDRB);

    prep_b<<<V + 1, 256, 0, stream>>>(adj, W, ATb, Wb);

    const size_t perBuf = (size_t)CHSTRIDE * 2;      // bytes per batch per bf16 buffer
    const size_t avail = ws_size > HDRB ? ws_size - HDRB : 0;
    int nbc = (int)(avail / (3 * perBuf));           // p1 + p2 + p3
    if (nbc < 1) nbc = 1;                            // requires ws >= ~17.5 MB
    if (nbc > B_) nbc = B_;

    for (int b0 = 0; b0 < B_; b0 += nbc) {
        const int nb = (B_ - b0 < nbc) ? (B_ - b0) : nbc;
        const float* xb = x + (size_t)b0 * CHSTRIDE;
        float* outb = out + (size_t)b0 * CHSTRIDE;
        u16* p1 = hbuf;
        u16* p2 = hbuf + (size_t)nbc * CHSTRIDE;
        u16* p3 = hbuf + (size_t)2 * nbc * CHSTRIDE;

        const dim3 pg(NFLAT / 64, 2, nb);            // (84, 2, nb)
        prop_s<true><<<pg, 256, 0, stream>>>((const void*)xb, ATb, p1);
        prop_s<false><<<pg, 256, 0, stream>>>((const void*)p1, ATb, p2);
        prop_s<false><<<pg, 256, 0, stream>>>((const void*)p2, ATb, p3);

        outconv_b<<<dim3(PLANE / 64, nb), 256, 0, stream>>>(xb, p1, p2, p3, Wb, bias, outb);
    }
}